// Round 3
// baseline (8215.165 us; speedup 1.0000x reference)
//
#include <hip/hip_runtime.h>
#include <cstdint>

// CharRNN fused kernel, round 7 — MI355X (gfx950).
//
// Topology: 8 clusters x 16 members = 128 wgs. Cluster c owns batch rows
// [16c,16c+16). Member m owns hidden outputs [32m,32m+32) (W_hh bf16 hi+lo
// register-resident) and vocab rows [8m,8m+8) of W_fc (k split, waves 2/3).
//
// r5 (3018us, passed): flag-release protocol, all exchange ops agent-scope
// (sc0 sc1 -> LLC round trips ~700-900cy each, serialized per step).
// r6 (FAILED, no profile): added plain-store writer fast path — hang-capable
// if plain-store->sc0-poll visibility model is wrong. Cause unknown
// (infra flake also possible).
//
// Round-7: hang-free XCD-local fast path.
//  - WRITER: byte-identical to r5 — ALL stores agent-scope sc1, vmcnt(0)
//    ack, then sc1 flag store. sc1 stores write-through the local XCD L2
//    en route to the LLC, so the line is valid at BOTH levels.
//  - READER: when all 16 cluster members share an XCD (runtime check via
//    s_getreg HW_REG_XCC_ID, published through agent-scope slots), polls
//    and sweeps use sc0-ONLY loads (bypass L1, served by local L2,
//    ~250-300cy) instead of sc0sc1 (~700-900cy). Both load flavors are
//    individually sound against sc1-stored data.
//  - ESCAPE HATCH: if an sc0 poll doesn't see the flag within 64Ki spins,
//    the WG permanently degrades (sticky) to pure r5 agent-scope reads.
//    Worst case = r5 behavior; unbounded spin impossible on the fast path.

typedef short bf16x8 __attribute__((ext_vector_type(8)));
typedef float f32x4 __attribute__((ext_vector_type(4)));

#define VOCAB 128
#define EMB   16
#define HID   512
#define TT    1024
#define NCL   8      // clusters
#define BB    16     // batch rows per cluster
#define JC    32     // hidden outputs per member
#define NWG   128
#define CLW   8192               // dwords per cluster per gen (hi 4096 + lo 4096)
#define BUFW  (NCL * CLW)        // 65536 dwords per generation buffer
#define FLAGOFF (2 * BUFW)       // u32 index of flag region (8 x 32 u32)
#define XCDOFF  (FLAGOFF + NCL * 32)  // u32 index of per-WG xcd slots (128)
#define PJC   33                 // padded ep stride

__device__ __forceinline__ unsigned short f2bf(float f) {
  uint32_t u = __builtin_bit_cast(uint32_t, f);
  u += 0x7FFFu + ((u >> 16) & 1u);
  return (unsigned short)(u >> 16);
}
__device__ __forceinline__ float bf2f(unsigned short s) {
  uint32_t u = (uint32_t)s << 16;
  return __builtin_bit_cast(float, u);
}
__device__ __forceinline__ float ftanh(float z) {
  z = fminf(15.f, fmaxf(-15.f, z));
  float e = __expf(2.f * z);
  return (e - 1.f) * __builtin_amdgcn_rcpf(e + 1.f);
}
__device__ __forceinline__ uint32_t aload(const uint32_t* p) {
  return __hip_atomic_load(p, __ATOMIC_RELAXED, __HIP_MEMORY_SCOPE_AGENT);
}
__device__ __forceinline__ void astore(uint32_t* p, uint32_t v) {
  __hip_atomic_store(p, v, __ATOMIC_RELAXED, __HIP_MEMORY_SCOPE_AGENT);
}

__global__ __launch_bounds__(256, 1) void charrnn_kernel(
    const int* __restrict__ xin,
    const float* __restrict__ emb,
    const float* __restrict__ wih,
    const float* __restrict__ whh,
    const float* __restrict__ bih,
    const float* __restrict__ bhh,
    const float* __restrict__ wfc,
    const float* __restrict__ bfc,
    float* __restrict__ out,
    uint32_t* __restrict__ hx)
{
  // frag-order h state: idx = ks*512 + lane*8 + j  (lane = quad_k*16 + row)
  __shared__ __align__(16) unsigned short a_hi[16 * 512];   // 16 KB
  __shared__ __align__(16) unsigned short a_lo[16 * 512];   // 16 KB
  __shared__ float ep[VOCAB * PJC];                         // 16.9 KB
  __shared__ unsigned char xtok[BB * TT];                   // 16 KB
  __shared__ __align__(16) float red[2][256];               // 2 KB logits partials
  __shared__ uint32_t s_xcd[16];
  __shared__ int s_fastf;

  const int tid  = threadIdx.x;
  const int wave = tid >> 6;
  const int lane = tid & 63;
  const int col  = lane & 15;
  const int quad = lane >> 4;
  const int cl   = blockIdx.x & 7;   // members of a cluster share blockIdx mod 8
  const int m    = blockIdx.x >> 3;  // -> same XCD under round-robin (perf hint)

  // ---- weight fragments -> registers (global gather, one-time) ----
  bf16x8 wfh[16], wfl[16], wfcf[8];
  if (wave < 2) {
    const int nrow = m * JC + wave * 16 + col;
    const float* wr = whh + (size_t)nrow * HID + quad * 8;
    #pragma unroll
    for (int ks = 0; ks < 16; ++ks) {
      bf16x8 hi, lo;
      #pragma unroll
      for (int j = 0; j < 8; ++j) {
        float w = wr[ks * 32 + j];
        unsigned short h = f2bf(w);
        hi[j] = (short)h;
        lo[j] = (short)f2bf(w - bf2f(h));
      }
      wfh[ks] = hi; wfl[ks] = lo;
    }
  } else {
    const int vrow = m * 8 + (col & 7);
    const float* wr = wfc + (size_t)vrow * HID + (wave - 2) * 256 + quad * 8;
    #pragma unroll
    for (int ks = 0; ks < 8; ++ks) {
      bf16x8 f;
      #pragma unroll
      for (int j = 0; j < 8; ++j) f[j] = (short)f2bf(wr[ks * 32 + j]);
      wfcf[ks] = f;
    }
  }
  const float bfcr = bfc[m * 8 + (col & 7)];

  // ---- LDS init: h0 = 0, ep table, tokens ----
  for (int i = tid; i < 16 * 512; i += 256) { a_hi[i] = 0; a_lo[i] = 0; }
  for (int i = tid; i < VOCAB * JC; i += 256) {
    int v = i >> 5, jl = i & 31;
    int jg = m * JC + jl;
    float s = bih[jg] + bhh[jg];
    #pragma unroll
    for (int e = 0; e < EMB; ++e) s += emb[v * EMB + e] * wih[jg * EMB + e];
    ep[v * PJC + jl] = s;
  }
  for (int i = tid; i < BB * TT; i += 256) {
    int b = i >> 10, t = i & 1023;
    xtok[i] = (unsigned char)xin[(cl * BB + b) * TT + t];
  }

  // ---- one-time XCD co-residency agreement (agent scope) ----
  uint32_t myxcd;
  asm volatile("s_getreg_b32 %0, hwreg(HW_REG_XCC_ID)" : "=s"(myxcd));
  myxcd &= 0xFFu;
  if (tid == 0) astore(hx + XCDOFF + blockIdx.x, myxcd + 1u);
  if (tid < 16) {
    uint32_t v;
    do { v = aload(hx + XCDOFF + tid * 8 + cl); } while (v == 0u);
    s_xcd[tid] = v;
  }
  __syncthreads();
  if (tid == 0) {
    int ok = 1;
    #pragma unroll
    for (int i = 1; i < 16; ++i) ok &= (s_xcd[i] == s_xcd[0]);
    s_fastf = ok;
  }
  __syncthreads();
  const bool fastmap = (s_fastf != 0);   // block-uniform

  // ---- main time loop ----
  uint32_t* const flags = hx + FLAGOFF + cl * 32;   // one 128B line per cluster
  const uint32_t* const fp = flags + (lane & 31);
  f32x4 prev_lacc = {0.f, 0.f, 0.f, 0.f};
  bool deg = !fastmap;   // sticky degrade -> pure r5 agent-scope reads

  #pragma unroll 1
  for (int t = 0; t <= TT + 1; ++t) {
    const int par = t & 1;

    // -- phase A: logits partials (computed in prior C) to LDS --
    if (wave >= 2 && t >= 2) {
      *(f32x4*)&red[wave - 2][lane * 4] = prev_lacc;
    }

    // -- phase B: flag gate, then coalesced sweep straight into LDS --
    if (t >= 1 && t <= TT) {
      // gate: sc0 poll (local L2) with bounded spin, else agent poll
      bool seen = false;
      if (!deg) {
        for (int s = 0; s < 65536 && !seen; ++s) {
          uint32_t f;
          asm volatile("global_load_dword %0, %1, off sc0\n\t"
                       "s_waitcnt vmcnt(0)"
                       : "=&v"(f) : "v"(fp) : "memory");
          seen = __all((int)(f >= (uint32_t)t)) != 0;
        }
        if (!seen) deg = true;   // sc0 staleness pathology: degrade forever
      }
      if (!seen) {
        uint32_t f;
        do { f = aload(fp); } while (__all((int)(f >= (uint32_t)t)) == 0);
      }
      asm volatile("" ::: "memory");   // keep sweep loads after the gate

      const uint32_t* src = hx + par * BUFW + cl * CLW + tid;
      uint32_t v[32];
      if (!deg) {
        // sc0-only sweep: bypass L1, served by local XCD L2
        #pragma unroll
        for (int g = 0; g < 8; ++g) {
          asm volatile("global_load_dword %0, %4, off sc0\n\t"
                       "global_load_dword %1, %4, off offset:1024 sc0\n\t"
                       "global_load_dword %2, %4, off offset:2048 sc0\n\t"
                       "global_load_dword %3, %4, off offset:3072 sc0"
                       : "=&v"(v[4 * g]), "=&v"(v[4 * g + 1]),
                         "=&v"(v[4 * g + 2]), "=&v"(v[4 * g + 3])
                       : "v"(src + g * 1024));
        }
        asm volatile("s_waitcnt vmcnt(0)" ::: "memory");
        __builtin_amdgcn_sched_barrier(0);
      } else {
        // agent sweep (r5): via coherence point
        #pragma unroll
        for (int i = 0; i < 32; ++i) v[i] = aload(src + 256 * i);
      }
      #pragma unroll
      for (int i = 0; i < 16; ++i)
        *(uint32_t*)&a_hi[(tid + 256 * i) * 2] = v[i];
      #pragma unroll
      for (int i = 0; i < 16; ++i)
        *(uint32_t*)&a_lo[(tid + 256 * i) * 2] = v[16 + i];
    }
    __syncthreads();  // B1: lds_a(gen t) ready; red stored

    // -- phase C --
    if (wave < 2) {
      // recurrence: gen t -> gen t+1 (3-term hi/lo MFMA), publish + flag
      // (writer side byte-identical to r5: all stores agent-scope sc1)
      if (t < TT) {
        f32x4 acc0 = {0.f,0.f,0.f,0.f}, acc1 = {0.f,0.f,0.f,0.f}, acc2 = {0.f,0.f,0.f,0.f};
        #pragma unroll
        for (int ks = 0; ks < 16; ++ks) {
          bf16x8 ah = *(const bf16x8*)&a_hi[ks * 512 + lane * 8];
          bf16x8 al = *(const bf16x8*)&a_lo[ks * 512 + lane * 8];
          acc0 = __builtin_amdgcn_mfma_f32_16x16x32_bf16(ah, wfh[ks], acc0, 0, 0, 0);
          acc1 = __builtin_amdgcn_mfma_f32_16x16x32_bf16(al, wfh[ks], acc1, 0, 0, 0);
          acc2 = __builtin_amdgcn_mfma_f32_16x16x32_bf16(ah, wfl[ks], acc2, 0, 0, 0);
        }
        const int jl = wave * 16 + col;
        // frag-order global dest: ks = m; qk = wave*2 + (col>>3); j = col&7.
        // even lanes store hi-pairs, odd lanes store lo-pairs (lane^1 shuffle).
        uint32_t* wb = hx + ((t + 1) & 1) * BUFW + cl * CLW
                     + ((lane & 1) ? 4096 : 0)
                     + m * 256 + (wave * 2 + (col >> 3)) * 64 + ((col & 7) >> 1);
        #pragma unroll
        for (int i = 0; i < 4; ++i) {
          const int b = quad * 4 + i;
          float z = acc0[i] + acc1[i] + acc2[i]
                  + ep[(int)xtok[b * TT + t] * PJC + jl];
          float h = ftanh(z);
          unsigned short hi = f2bf(h);
          float lof = h - bf2f(hi);
          unsigned short lo = f2bf(lof);
          uint32_t pk = (uint32_t)hi | ((uint32_t)lo << 16);
          uint32_t pp = (uint32_t)__shfl_xor((int)pk, 1);
          uint32_t word = (lane & 1) ? ((pp >> 16) | (pk & 0xFFFF0000u))
                                     : ((pk & 0xFFFFu) | (pp << 16));
          astore(wb + b * 4, word);
        }
        // release: sc1 stores acked at the coherence point, then flag.
        asm volatile("s_waitcnt vmcnt(0)" ::: "memory");
        if (lane == 0) astore(&flags[m * 2 + wave], (uint32_t)(t + 1));
      }
    } else {
      // reduce + store logits for time t-2 (wave 2; partials in red from A)
      if (wave == 2 && t >= 2 && col < 8) {
        #pragma unroll
        for (int i = 0; i < 4; ++i) {
          const int b = quad * 4 + i;
          float s = red[0][lane * 4 + i] + red[1][lane * 4 + i] + bfcr;
          out[((size_t)(cl * BB + b) * TT + (t - 2)) * VOCAB + m * 8 + col] = s;
        }
      }
      // logits MFMA for time t-1 (k-half per wave, hi+lo terms)
      if (t >= 1 && t <= TT) {
        f32x4 lacc = {0.f, 0.f, 0.f, 0.f};
        const int kb = (wave - 2) * 8;
        #pragma unroll
        for (int ks = 0; ks < 8; ++ks) {
          bf16x8 ah = *(const bf16x8*)&a_hi[(kb + ks) * 512 + lane * 8];
          bf16x8 al = *(const bf16x8*)&a_lo[(kb + ks) * 512 + lane * 8];
          lacc = __builtin_amdgcn_mfma_f32_16x16x32_bf16(ah, wfcf[ks], lacc, 0, 0, 0);
          lacc = __builtin_amdgcn_mfma_f32_16x16x32_bf16(al, wfcf[ks], lacc, 0, 0, 0);
        }
        prev_lacc = lacc;
      }
    }
    __syncthreads();  // B2: lds_a consumed; red consumed
  }
}

extern "C" void kernel_launch(void* const* d_in, const int* in_sizes, int n_in,
                              void* d_out, int out_size, void* d_ws, size_t ws_size,
                              hipStream_t stream) {
  (void)in_sizes; (void)n_in; (void)out_size;
  if (ws_size < (size_t)FLAGOFF * sizeof(uint32_t) + 4096) return;  // 512 KB + ctrl

  const int*   x    = (const int*)d_in[0];
  const float* embp = (const float*)d_in[1];
  const float* W_ih = (const float*)d_in[2];
  const float* W_hh = (const float*)d_in[3];
  const float* b_ih = (const float*)d_in[4];
  const float* b_hh = (const float*)d_in[5];
  const float* W_fc = (const float*)d_in[6];
  const float* b_fc = (const float*)d_in[7];

  // zero the per-cluster flag lines (8x32 u32) AND the 128 xcd-id slots
  hipMemsetAsync((uint32_t*)d_ws + FLAGOFF, 0,
                 (NCL * 32 + NWG) * sizeof(uint32_t), stream);

  charrnn_kernel<<<NWG, 256, 0, stream>>>(x, embp, W_ih, W_hh, b_ih, b_hh, W_fc, b_fc,
                                          (float*)d_out, (uint32_t*)d_ws);
}

// Round 5
// 3458.866 us; speedup vs baseline: 2.3751x; 2.3751x over previous
//
#include <hip/hip_runtime.h>
#include <cstdint>

// CharRNN fused kernel, round 9 — MI355X (gfx950).
//
// Topology: 8 clusters x 16 members = 128 wgs. Cluster c owns batch rows
// [16c,16c+16). Member m owns hidden outputs [32m,32m+32) (W_hh bf16 hi+lo
// register-resident) and vocab rows [8m,8m+8) of W_fc (k split, waves 2/3).
//
// Protocol history (measured):
//  r5 (3018us): flag protocol, all agent(sc1): ack(~900)+flagprop(~700)+
//     poll(~400-800)+sweep(~900) serialized = ~7k cy/step.
//  r6/r7/r8: XCD-local fast paths — DEAD. r7+r8 measurements triangulate:
//     sc0 loads can hit CU-private L1 and NOTHING short of device-scope
//     invalidates it (sc1-store->sc0-load stale 65536 polls; plain-store->
//     sc0-load stale too). Retreat to proven sc1 semantics.
//
// Round-9: tag-validated optimistic exchange (kills ack+flagprop+poll legs).
//  - format: word = (q21 << 11) | tag11, q = round(h * 2^20) clamped —
//    EXACTLY r4's proven numerics (absmax 7.8e-3). tag = gen & 0x7FF.
//  - layout: frag-linear per cluster (idx = ks*512 + lane*8 + e), so the
//    reader's 32 loads/thread are coalesced AND its LDS writes are linear.
//  - writer: tagged stores, fire-and-forget (NO vmcnt ack), then flag.
//    Flag is only a retry-rate limiter now; tags carry correctness.
//  - reader: 1 SPECULATIVE batched sweep at phase-B entry (overlaps remote
//    store latency); on tag miss -> r5 flag-poll gate -> tag-validated
//    batched retries. Bounded extra traffic (<=2x r5), unlike r2's storm.
//  - tag soundness: gen t vs t-2 differ mod 2048; cross-launch residue is
//    overwritten by gen<=2 (expects tags 1,2; residue has 0x3FF/0x400);
//    poison 0xAA (tag 682) only present at t<=2. Single u32 stores atomic.
//  - overwrite race: member A stores gen t+2 only after A's sweep of gen
//    t+1 was CLEAN, which requires every member B stored gen t+1, which
//    happens after B's own gen-t sweep (B1 barrier). Unchanged from r5.
//  - unpack (reader): q->f32->hi/lo bf16 split (r4 math), v_perm pack,
//    shfl_xor(1) pairing, stride-1 ds_write_b32 (conflict-free; r4's 2e8
//    bank conflicts came from its strided b16 writes — eliminated).

typedef short bf16x8 __attribute__((ext_vector_type(8)));
typedef float f32x4 __attribute__((ext_vector_type(4)));

#define VOCAB 128
#define EMB   16
#define HID   512
#define TT    1024
#define NCL   8      // clusters
#define BB    16     // batch rows per cluster
#define JC    32     // hidden outputs per member
#define NWG   128
#define CLW   8192               // words per cluster per gen (frag-linear)
#define BUFW  (NCL * CLW)        // 65536 words per generation buffer
#define FLAGOFF (2 * BUFW)       // u32 index of flag region (8 x 32 u32)
#define PJC   33                 // padded ep stride

__device__ __forceinline__ unsigned short f2bf(float f) {
  uint32_t u = __builtin_bit_cast(uint32_t, f);
  u += 0x7FFFu + ((u >> 16) & 1u);
  return (unsigned short)(u >> 16);
}
__device__ __forceinline__ float bf2f(unsigned short s) {
  uint32_t u = (uint32_t)s << 16;
  return __builtin_bit_cast(float, u);
}
__device__ __forceinline__ float ftanh(float z) {
  z = fminf(15.f, fmaxf(-15.f, z));
  float e = __expf(2.f * z);
  return (e - 1.f) * __builtin_amdgcn_rcpf(e + 1.f);
}
__device__ __forceinline__ uint32_t aload(const uint32_t* p) {
  return __hip_atomic_load(p, __ATOMIC_RELAXED, __HIP_MEMORY_SCOPE_AGENT);
}
__device__ __forceinline__ void astore(uint32_t* p, uint32_t v) {
  __hip_atomic_store(p, v, __ATOMIC_RELAXED, __HIP_MEMORY_SCOPE_AGENT);
}

__global__ __launch_bounds__(256, 1) void charrnn_kernel(
    const int* __restrict__ xin,
    const float* __restrict__ emb,
    const float* __restrict__ wih,
    const float* __restrict__ whh,
    const float* __restrict__ bih,
    const float* __restrict__ bhh,
    const float* __restrict__ wfc,
    const float* __restrict__ bfc,
    float* __restrict__ out,
    uint32_t* __restrict__ hx)
{
  // frag-order h state: idx = ks*512 + lane*8 + e  (lane = quad_k*16 + row)
  __shared__ __align__(16) unsigned short a_hi[16 * 512];   // 16 KB
  __shared__ __align__(16) unsigned short a_lo[16 * 512];   // 16 KB
  __shared__ float ep[VOCAB * PJC];                         // 16.9 KB
  __shared__ unsigned char xtok[BB * TT];                   // 16 KB
  __shared__ __align__(16) float red[2][256];               // 2 KB logits partials

  uint32_t* const a_hi32 = (uint32_t*)a_hi;
  uint32_t* const a_lo32 = (uint32_t*)a_lo;

  const int tid  = threadIdx.x;
  const int wave = tid >> 6;
  const int lane = tid & 63;
  const int col  = lane & 15;
  const int quad = lane >> 4;
  const int cl   = blockIdx.x & 7;   // members of a cluster share blockIdx mod 8
  const int m    = blockIdx.x >> 3;

  // ---- weight fragments -> registers (global gather, one-time) ----
  bf16x8 wfh[16], wfl[16], wfcf[8];
  if (wave < 2) {
    const int nrow = m * JC + wave * 16 + col;
    const float* wr = whh + (size_t)nrow * HID + quad * 8;
    #pragma unroll
    for (int ks = 0; ks < 16; ++ks) {
      bf16x8 hi, lo;
      #pragma unroll
      for (int j = 0; j < 8; ++j) {
        float w = wr[ks * 32 + j];
        unsigned short h = f2bf(w);
        hi[j] = (short)h;
        lo[j] = (short)f2bf(w - bf2f(h));
      }
      wfh[ks] = hi; wfl[ks] = lo;
    }
  } else {
    const int vrow = m * 8 + (col & 7);
    const float* wr = wfc + (size_t)vrow * HID + (wave - 2) * 256 + quad * 8;
    #pragma unroll
    for (int ks = 0; ks < 8; ++ks) {
      bf16x8 f;
      #pragma unroll
      for (int j = 0; j < 8; ++j) f[j] = (short)f2bf(wr[ks * 32 + j]);
      wfcf[ks] = f;
    }
  }
  const float bfcr = bfc[m * 8 + (col & 7)];

  // ---- LDS init: h0 = 0, ep table, tokens ----
  for (int i = tid; i < 16 * 512; i += 256) { a_hi[i] = 0; a_lo[i] = 0; }
  for (int i = tid; i < VOCAB * JC; i += 256) {
    int v = i >> 5, jl = i & 31;
    int jg = m * JC + jl;
    float s = bih[jg] + bhh[jg];
    #pragma unroll
    for (int e = 0; e < EMB; ++e) s += emb[v * EMB + e] * wih[jg * EMB + e];
    ep[v * PJC + jl] = s;
  }
  for (int i = tid; i < BB * TT; i += 256) {
    int b = i >> 10, t = i & 1023;
    xtok[i] = (unsigned char)xin[(cl * BB + b) * TT + t];
  }
  __syncthreads();

  // ---- per-lane constants ----
  // writer frag-linear base: jg = m*32 + wave*16 + col (waves 0/1);
  // idx(b) = m*512 + (wave*2 + (col>>3))*128 + b*8 + (col&7)
  const int jl = wave * 16 + col;
  const int C0 = m * 512 + ((wave * 2 + (col >> 3)) << 7) + (col & 7);
  const float rcp20 = 1.f / 1048576.f;
  const uint32_t hsel = 0xFFFF0000u;
  // reader repack: even tid -> a_hi words, odd tid -> a_lo words
  uint32_t* const dbase = (tid & 1) ? a_lo32 : a_hi32;
  const uint32_t psel = (tid & 1) ? 0x03020706u : 0x05040100u;
  const int dword0 = tid >> 1;

  uint32_t* const flags = hx + FLAGOFF + cl * 32;   // one 128B line per cluster
  const uint32_t* const fp = flags + (lane & 31);
  f32x4 prev_lacc = {0.f, 0.f, 0.f, 0.f};

  #pragma unroll 1
  for (int t = 0; t <= TT + 1; ++t) {
    const int par = t & 1;

    // -- phase A: logits partials (computed in prior C) to LDS --
    if (wave >= 2 && t >= 2) {
      *(f32x4*)&red[wave - 2][lane * 4] = prev_lacc;
    }

    // -- phase B: speculative tagged sweep; gate+retry only on miss --
    if (t >= 1 && t <= TT) {
      const uint32_t tag = (uint32_t)t & 0x7FFu;
      const uint32_t* src = hx + par * BUFW + cl * CLW + tid;
      uint32_t v[32];
      // round 1: speculative (overlaps remote writers' store latency)
      #pragma unroll
      for (int i = 0; i < 32; ++i) v[i] = aload(src + 256 * i);
      uint32_t bad = 0;
      #pragma unroll
      for (int i = 0; i < 32; ++i) bad |= v[i] ^ tag;
      bad &= 0x7FFu;
      if (__any((int)bad)) {
        // storm cap: wait on the shared flag line, then tag-validated retries
        uint32_t f;
        do { f = aload(fp); } while (__all((int)(f >= (uint32_t)t)) == 0);
        for (;;) {
          #pragma unroll
          for (int i = 0; i < 32; ++i) v[i] = aload(src + 256 * i);
          bad = 0;
          #pragma unroll
          for (int i = 0; i < 32; ++i) bad |= v[i] ^ tag;
          bad &= 0x7FFu;
          if (__any((int)bad) == 0) break;
        }
      }
      // unpack: word i holds frag idx n = tid + 256*i; pair via lane^1;
      // even tid writes a_hi32[n>>1], odd tid writes a_lo32[n>>1].
      #pragma unroll
      for (int i = 0; i < 32; ++i) {
        float h = (float)(((int)v[i]) >> 11) * rcp20;
        uint32_t uh = __builtin_bit_cast(uint32_t, h) & hsel;
        float l = h - __builtin_bit_cast(float, uh);
        // pk = {lo16: hi-bf16, hi16: lo-bf16}
        uint32_t pk = __builtin_amdgcn_perm(__builtin_bit_cast(uint32_t, l),
                                            uh, 0x07060302u);
        uint32_t pp = (uint32_t)__shfl_xor((int)pk, 1);
        // even: {hi(n), hi(n+1)}; odd: {lo(n-1), lo(n)} — one v_perm each
        uint32_t wd = __builtin_amdgcn_perm(pp, pk, psel);
        dbase[128 * i + dword0] = wd;
      }
    }
    __syncthreads();  // B1: lds_a(gen t) ready; red stored

    // -- phase C --
    if (wave < 2) {
      // recurrence: gen t -> gen t+1 (3-term hi/lo MFMA), tagged publish
      if (t < TT) {
        f32x4 acc0 = {0.f,0.f,0.f,0.f}, acc1 = {0.f,0.f,0.f,0.f}, acc2 = {0.f,0.f,0.f,0.f};
        #pragma unroll
        for (int ks = 0; ks < 16; ++ks) {
          bf16x8 ah = *(const bf16x8*)&a_hi[ks * 512 + lane * 8];
          bf16x8 al = *(const bf16x8*)&a_lo[ks * 512 + lane * 8];
          acc0 = __builtin_amdgcn_mfma_f32_16x16x32_bf16(ah, wfh[ks], acc0, 0, 0, 0);
          acc1 = __builtin_amdgcn_mfma_f32_16x16x32_bf16(al, wfh[ks], acc1, 0, 0, 0);
          acc2 = __builtin_amdgcn_mfma_f32_16x16x32_bf16(ah, wfl[ks], acc2, 0, 0, 0);
        }
        const uint32_t ntag = (uint32_t)(t + 1) & 0x7FFu;
        uint32_t* wb = hx + ((t + 1) & 1) * BUFW + cl * CLW + C0;
        #pragma unroll
        for (int i = 0; i < 4; ++i) {
          const int b = quad * 4 + i;
          float z = acc0[i] + acc1[i] + acc2[i]
                  + ep[(int)xtok[b * TT + t] * PJC + jl];
          float h = ftanh(z);
          int q = __float2int_rn(h * 1048576.f);
          q = max(min(q, 1048575), -1048576);
          astore(wb + b * 8, ((uint32_t)q << 11) | ntag);
        }
        // NO vmcnt ack: tags validate arrival. Flag = retry-rate limiter.
        asm volatile("" ::: "memory");
        if (lane == 0) astore(&flags[m * 2 + wave], (uint32_t)(t + 1));
      }
    } else {
      // reduce + store logits for time t-2 (wave 2; partials in red from A)
      if (wave == 2 && t >= 2 && col < 8) {
        #pragma unroll
        for (int i = 0; i < 4; ++i) {
          const int b = quad * 4 + i;
          float s = red[0][lane * 4 + i] + red[1][lane * 4 + i] + bfcr;
          out[((size_t)(cl * BB + b) * TT + (t - 2)) * VOCAB + m * 8 + col] = s;
        }
      }
      // logits MFMA (k-half per wave, hi+lo terms)
      if (t >= 1 && t <= TT) {
        f32x4 lacc = {0.f, 0.f, 0.f, 0.f};
        const int kb = (wave - 2) * 8;
        #pragma unroll
        for (int ks = 0; ks < 8; ++ks) {
          bf16x8 ah = *(const bf16x8*)&a_hi[(kb + ks) * 512 + lane * 8];
          bf16x8 al = *(const bf16x8*)&a_lo[(kb + ks) * 512 + lane * 8];
          lacc = __builtin_amdgcn_mfma_f32_16x16x32_bf16(ah, wfcf[ks], lacc, 0, 0, 0);
          lacc = __builtin_amdgcn_mfma_f32_16x16x32_bf16(al, wfcf[ks], lacc, 0, 0, 0);
        }
        prev_lacc = lacc;
      }
    }
    __syncthreads();  // B2: lds_a consumed; red consumed
  }
}

extern "C" void kernel_launch(void* const* d_in, const int* in_sizes, int n_in,
                              void* d_out, int out_size, void* d_ws, size_t ws_size,
                              hipStream_t stream) {
  (void)in_sizes; (void)n_in; (void)out_size;
  if (ws_size < (size_t)FLAGOFF * sizeof(uint32_t) + 4096) return;  // 512 KB + ctrl

  const int*   x    = (const int*)d_in[0];
  const float* embp = (const float*)d_in[1];
  const float* W_ih = (const float*)d_in[2];
  const float* W_hh = (const float*)d_in[3];
  const float* b_ih = (const float*)d_in[4];
  const float* b_hh = (const float*)d_in[5];
  const float* W_fc = (const float*)d_in[6];
  const float* b_fc = (const float*)d_in[7];

  // zero the per-cluster flag lines (8 x 32 u32); data region needs no init
  // (tag protocol rejects poison/residue; see header comment)
  hipMemsetAsync((uint32_t*)d_ws + FLAGOFF, 0, NCL * 32 * sizeof(uint32_t), stream);

  charrnn_kernel<<<NWG, 256, 0, stream>>>(x, embp, W_ih, W_hh, b_ih, b_hh, W_fc, b_fc,
                                          (float*)d_out, (uint32_t*)d_ws);
}